// Round 1
// baseline (1675.623 us; speedup 1.0000x reference)
//
#include <hip/hip_runtime.h>

// GraphSAGE (pool aggregator), 2 layers + linear head, all fp32.
// N=100000, E=1600000, IN=128, H=64, C=2.

// ---------------- GEMM: pooled1 = relu(x @ W[128x128] + b) ----------------
// 32 rows/block, 256 threads, each thread 4 rows x 4 cols.
__global__ __launch_bounds__(256) void gemm_pool1(
    const float* __restrict__ A, const float* __restrict__ W,
    const float* __restrict__ b, float* __restrict__ out, int n) {
  __shared__ float As[128][36];  // transposed [k][row], 32 rows padded to 36
  const int t = threadIdx.x;
  const int row0 = blockIdx.x * 32;
  const int tr = t & 31;   // row within tile
  const int tk = t >> 5;   // 0..7
  int gr = row0 + tr; if (gr >= n) gr = n - 1;
#pragma unroll
  for (int i = 0; i < 4; ++i) {
    const int k4 = tk * 16 + i * 4;
    const float4 v = *(const float4*)(A + (size_t)gr * 128 + k4);
    As[k4 + 0][tr] = v.x; As[k4 + 1][tr] = v.y;
    As[k4 + 2][tr] = v.z; As[k4 + 3][tr] = v.w;
  }
  __syncthreads();
  const int cg = t & 31, rg = t >> 5;
  const int c0 = cg * 4;
  float acc[4][4] = {};
#pragma unroll 4
  for (int k = 0; k < 128; ++k) {
    const float4 w = *(const float4*)(W + k * 128 + c0);
    const float4 a = *(const float4*)(&As[k][rg * 4]);
    acc[0][0] = fmaf(a.x, w.x, acc[0][0]);
    acc[0][1] = fmaf(a.x, w.y, acc[0][1]);
    acc[0][2] = fmaf(a.x, w.z, acc[0][2]);
    acc[0][3] = fmaf(a.x, w.w, acc[0][3]);
    acc[1][0] = fmaf(a.y, w.x, acc[1][0]);
    acc[1][1] = fmaf(a.y, w.y, acc[1][1]);
    acc[1][2] = fmaf(a.y, w.z, acc[1][2]);
    acc[1][3] = fmaf(a.y, w.w, acc[1][3]);
    acc[2][0] = fmaf(a.z, w.x, acc[2][0]);
    acc[2][1] = fmaf(a.z, w.y, acc[2][1]);
    acc[2][2] = fmaf(a.z, w.z, acc[2][2]);
    acc[2][3] = fmaf(a.z, w.w, acc[2][3]);
    acc[3][0] = fmaf(a.w, w.x, acc[3][0]);
    acc[3][1] = fmaf(a.w, w.y, acc[3][1]);
    acc[3][2] = fmaf(a.w, w.z, acc[3][2]);
    acc[3][3] = fmaf(a.w, w.w, acc[3][3]);
  }
  const float4 bb = *(const float4*)(b + c0);
#pragma unroll
  for (int r = 0; r < 4; ++r) {
    const int orow = row0 + rg * 4 + r;
    if (orow < n) {
      float4 o;
      o.x = fmaxf(acc[r][0] + bb.x, 0.f);
      o.y = fmaxf(acc[r][1] + bb.y, 0.f);
      o.z = fmaxf(acc[r][2] + bb.z, 0.f);
      o.w = fmaxf(acc[r][3] + bb.w, 0.f);
      *(float4*)(out + (size_t)orow * 128 + c0) = o;
    }
  }
}

// ---------------- Edge segment-max via u32 atomicMax ----------------
// pooled >= 0 (ReLU), so uint bit-pattern compare == float compare,
// and agg init 0 == DGL's isolated-node fill.
template <int D>
__global__ __launch_bounds__(256) void edge_max_kernel(
    const int* __restrict__ src, const int* __restrict__ dst,
    const float* __restrict__ pooled, unsigned int* __restrict__ agg, int nE) {
  constexpr int TPE = D / 4;  // threads per edge
  const long long tid = (long long)blockIdx.x * 256 + threadIdx.x;
  const int e = (int)(tid / TPE);
  if (e >= nE) return;
  const int f = ((int)(tid % TPE)) * 4;
  const int s = src[e], d = dst[e];
  const float4 v = *(const float4*)(pooled + (size_t)s * D + f);
  unsigned int* a = agg + (size_t)d * D + f;
  const uint4 cur = *(const uint4*)a;
  const unsigned ux = __float_as_uint(v.x);
  const unsigned uy = __float_as_uint(v.y);
  const unsigned uz = __float_as_uint(v.z);
  const unsigned uw = __float_as_uint(v.w);
  if (ux > cur.x) atomicMax(a + 0, ux);
  if (uy > cur.y) atomicMax(a + 1, uy);
  if (uz > cur.z) atomicMax(a + 2, uz);
  if (uw > cur.w) atomicMax(a + 3, uw);
}

// ---------------- h = relu?(A @ Wa [+ G @ Wg] + bias), DOUT=64 ----------------
// 64 rows/block, 256 threads, each thread 4 rows x 4 cols.
template <int DIN, bool DUAL, bool RELU>
__global__ __launch_bounds__(256) void gemm_h(
    const float* __restrict__ A, const float* __restrict__ Wa,
    const float* __restrict__ G, const float* __restrict__ Wg,
    const float* __restrict__ bias, float* __restrict__ out, int n) {
  __shared__ float S[DIN][68];  // transposed [k][row], 64 rows padded to 68
  const int t = threadIdx.x;
  const int row0 = blockIdx.x * 64;
  const int tr = t & 63;   // row
  const int tk = t >> 6;   // 0..3
  const int cg = t & 15, rg = t >> 4;
  const int c0 = cg * 4;
  float acc[4][4] = {};
  int gr = row0 + tr; if (gr >= n) gr = n - 1;
  const int NPASS = DUAL ? 2 : 1;
  for (int pass = 0; pass < NPASS; ++pass) {
    const float* __restrict__ P = pass ? G : A;
    const float* __restrict__ W = pass ? Wg : Wa;
    constexpr int PER_T = DIN / 16;  // float4s per thread (8 for 128, 4 for 64)
#pragma unroll
    for (int i = 0; i < PER_T; ++i) {
      const int k4 = (tk * PER_T + i) * 4;
      const float4 v = *(const float4*)(P + (size_t)gr * DIN + k4);
      S[k4 + 0][tr] = v.x; S[k4 + 1][tr] = v.y;
      S[k4 + 2][tr] = v.z; S[k4 + 3][tr] = v.w;
    }
    __syncthreads();
#pragma unroll 4
    for (int k = 0; k < DIN; ++k) {
      const float4 w = *(const float4*)(W + k * 64 + c0);
      const float4 a = *(const float4*)(&S[k][rg * 4]);
      acc[0][0] = fmaf(a.x, w.x, acc[0][0]);
      acc[0][1] = fmaf(a.x, w.y, acc[0][1]);
      acc[0][2] = fmaf(a.x, w.z, acc[0][2]);
      acc[0][3] = fmaf(a.x, w.w, acc[0][3]);
      acc[1][0] = fmaf(a.y, w.x, acc[1][0]);
      acc[1][1] = fmaf(a.y, w.y, acc[1][1]);
      acc[1][2] = fmaf(a.y, w.z, acc[1][2]);
      acc[1][3] = fmaf(a.y, w.w, acc[1][3]);
      acc[2][0] = fmaf(a.z, w.x, acc[2][0]);
      acc[2][1] = fmaf(a.z, w.y, acc[2][1]);
      acc[2][2] = fmaf(a.z, w.z, acc[2][2]);
      acc[2][3] = fmaf(a.z, w.w, acc[2][3]);
      acc[3][0] = fmaf(a.w, w.x, acc[3][0]);
      acc[3][1] = fmaf(a.w, w.y, acc[3][1]);
      acc[3][2] = fmaf(a.w, w.z, acc[3][2]);
      acc[3][3] = fmaf(a.w, w.w, acc[3][3]);
    }
    if (pass + 1 < NPASS) __syncthreads();
  }
  const float4 bb = *(const float4*)(bias + c0);
#pragma unroll
  for (int r = 0; r < 4; ++r) {
    const int orow = row0 + rg * 4 + r;
    if (orow < n) {
      float4 o;
      o.x = acc[r][0] + bb.x;
      o.y = acc[r][1] + bb.y;
      o.z = acc[r][2] + bb.z;
      o.w = acc[r][3] + bb.w;
      if (RELU) {
        o.x = fmaxf(o.x, 0.f); o.y = fmaxf(o.y, 0.f);
        o.z = fmaxf(o.z, 0.f); o.w = fmaxf(o.w, 0.f);
      }
      *(float4*)(out + (size_t)orow * 64 + c0) = o;
    }
  }
}

// ---------------- out[N x 2] = h2 @ W_out + b_out ----------------
__global__ __launch_bounds__(256) void out_linear(
    const float* __restrict__ h, const float* __restrict__ W,
    const float* __restrict__ b, float* __restrict__ out, int n) {
  const int node = blockIdx.x * 256 + threadIdx.x;
  if (node >= n) return;
  float a0 = b[0], a1 = b[1];
#pragma unroll
  for (int k = 0; k < 64; k += 4) {
    const float4 hv = *(const float4*)(h + (size_t)node * 64 + k);
    a0 = fmaf(hv.x, W[(k + 0) * 2 + 0], a0);
    a1 = fmaf(hv.x, W[(k + 0) * 2 + 1], a1);
    a0 = fmaf(hv.y, W[(k + 1) * 2 + 0], a0);
    a1 = fmaf(hv.y, W[(k + 1) * 2 + 1], a1);
    a0 = fmaf(hv.z, W[(k + 2) * 2 + 0], a0);
    a1 = fmaf(hv.z, W[(k + 2) * 2 + 1], a1);
    a0 = fmaf(hv.w, W[(k + 3) * 2 + 0], a0);
    a1 = fmaf(hv.w, W[(k + 3) * 2 + 1], a1);
  }
  float2 o; o.x = a0; o.y = a1;
  *(float2*)(out + (size_t)node * 2) = o;
}

extern "C" void kernel_launch(void* const* d_in, const int* in_sizes, int n_in,
                              void* d_out, int out_size, void* d_ws, size_t ws_size,
                              hipStream_t stream) {
  const float* x       = (const float*)d_in[0];
  const int*   src     = (const int*)d_in[1];
  const int*   dst     = (const int*)d_in[2];
  const float* W_pool1 = (const float*)d_in[3];
  const float* b_pool1 = (const float*)d_in[4];
  const float* W_self1 = (const float*)d_in[5];
  const float* W_neigh1= (const float*)d_in[6];
  const float* b1      = (const float*)d_in[7];
  const float* W_pool2 = (const float*)d_in[8];
  const float* b_pool2 = (const float*)d_in[9];
  const float* W_self2 = (const float*)d_in[10];
  const float* W_neigh2= (const float*)d_in[11];
  const float* b2      = (const float*)d_in[12];
  const float* W_out   = (const float*)d_in[13];
  const float* b_out   = (const float*)d_in[14];

  const int n  = in_sizes[0] / 128;
  const int nE = in_sizes[1];

  float* pooled = (float*)d_ws;                     // n*128 (layer2 reuses n*64)
  float* agg    = pooled + (size_t)n * 128;         // n*128 (layer2 reuses n*64)
  float* h1     = agg + (size_t)n * 128;            // n*64
  float* h2     = h1 + (size_t)n * 64;              // n*64
  float* outp   = (float*)d_out;

  // ---- layer 1 ----
  hipMemsetAsync(agg, 0, (size_t)n * 128 * sizeof(float), stream);
  gemm_pool1<<<(n + 31) / 32, 256, 0, stream>>>(x, W_pool1, b_pool1, pooled, n);
  {
    const long long tot = (long long)nE * 32;  // 128/4 threads per edge
    edge_max_kernel<128><<<(int)((tot + 255) / 256), 256, 0, stream>>>(
        src, dst, pooled, (unsigned int*)agg, nE);
  }
  gemm_h<128, true, true><<<(n + 63) / 64, 256, 0, stream>>>(
      x, W_self1, agg, W_neigh1, b1, h1, n);

  // ---- layer 2 (reuse pooled/agg buffers at n*64) ----
  hipMemsetAsync(agg, 0, (size_t)n * 64 * sizeof(float), stream);
  gemm_h<64, false, true><<<(n + 63) / 64, 256, 0, stream>>>(
      h1, W_pool2, nullptr, nullptr, b_pool2, pooled, n);
  {
    const long long tot = (long long)nE * 16;  // 64/4 threads per edge
    edge_max_kernel<64><<<(int)((tot + 255) / 256), 256, 0, stream>>>(
        src, dst, pooled, (unsigned int*)agg, nE);
  }
  gemm_h<64, true, true><<<(n + 63) / 64, 256, 0, stream>>>(
      h1, W_self2, agg, W_neigh2, b2, h2, n);

  // ---- head ----
  out_linear<<<(n + 255) / 256, 256, 0, stream>>>(h2, W_out, b_out, outp, n);
}

// Round 2
// 591.337 us; speedup vs baseline: 2.8336x; 2.8336x over previous
//
#include <hip/hip_runtime.h>

// GraphSAGE (pool aggregator), 2 layers + linear head, all fp32.
// N=100000, E=1600000, IN=128, H=64, C=2.
// Edge aggregation via per-call dst-CSR build + one-wave-per-dst max (no atomics
// in the hot phase; scatter's atomicAdd only permutes within-segment order,
// which max() is invariant to -> deterministic output).

// ---------------- GEMM: pooled1 = relu(x @ W[128x128] + b) ----------------
__global__ __launch_bounds__(256) void gemm_pool1(
    const float* __restrict__ A, const float* __restrict__ W,
    const float* __restrict__ b, float* __restrict__ out, int n) {
  __shared__ float As[128][36];
  const int t = threadIdx.x;
  const int row0 = blockIdx.x * 32;
  const int tr = t & 31;
  const int tk = t >> 5;
  int gr = row0 + tr; if (gr >= n) gr = n - 1;
#pragma unroll
  for (int i = 0; i < 4; ++i) {
    const int k4 = tk * 16 + i * 4;
    const float4 v = *(const float4*)(A + (size_t)gr * 128 + k4);
    As[k4 + 0][tr] = v.x; As[k4 + 1][tr] = v.y;
    As[k4 + 2][tr] = v.z; As[k4 + 3][tr] = v.w;
  }
  __syncthreads();
  const int cg = t & 31, rg = t >> 5;
  const int c0 = cg * 4;
  float acc[4][4] = {};
#pragma unroll 4
  for (int k = 0; k < 128; ++k) {
    const float4 w = *(const float4*)(W + k * 128 + c0);
    const float4 a = *(const float4*)(&As[k][rg * 4]);
    acc[0][0] = fmaf(a.x, w.x, acc[0][0]);
    acc[0][1] = fmaf(a.x, w.y, acc[0][1]);
    acc[0][2] = fmaf(a.x, w.z, acc[0][2]);
    acc[0][3] = fmaf(a.x, w.w, acc[0][3]);
    acc[1][0] = fmaf(a.y, w.x, acc[1][0]);
    acc[1][1] = fmaf(a.y, w.y, acc[1][1]);
    acc[1][2] = fmaf(a.y, w.z, acc[1][2]);
    acc[1][3] = fmaf(a.y, w.w, acc[1][3]);
    acc[2][0] = fmaf(a.z, w.x, acc[2][0]);
    acc[2][1] = fmaf(a.z, w.y, acc[2][1]);
    acc[2][2] = fmaf(a.z, w.z, acc[2][2]);
    acc[2][3] = fmaf(a.z, w.w, acc[2][3]);
    acc[3][0] = fmaf(a.w, w.x, acc[3][0]);
    acc[3][1] = fmaf(a.w, w.y, acc[3][1]);
    acc[3][2] = fmaf(a.w, w.z, acc[3][2]);
    acc[3][3] = fmaf(a.w, w.w, acc[3][3]);
  }
  const float4 bb = *(const float4*)(b + c0);
#pragma unroll
  for (int r = 0; r < 4; ++r) {
    const int orow = row0 + rg * 4 + r;
    if (orow < n) {
      float4 o;
      o.x = fmaxf(acc[r][0] + bb.x, 0.f);
      o.y = fmaxf(acc[r][1] + bb.y, 0.f);
      o.z = fmaxf(acc[r][2] + bb.z, 0.f);
      o.w = fmaxf(acc[r][3] + bb.w, 0.f);
      *(float4*)(out + (size_t)orow * 128 + c0) = o;
    }
  }
}

// ---------------- CSR build ----------------
__global__ __launch_bounds__(256) void hist_kernel(
    const int* __restrict__ dst, int* __restrict__ deg, int nE) {
  const int e = blockIdx.x * 256 + threadIdx.x;
  if (e < nE) atomicAdd(&deg[dst[e]], 1);
}

#define SCAN_CHUNK 2048
__global__ __launch_bounds__(256) void scan_partial(
    const int* __restrict__ deg, int* __restrict__ bsum, int n) {
  __shared__ int s[256];
  const int base = blockIdx.x * SCAN_CHUNK;
  int sum = 0;
  for (int i = threadIdx.x; i < SCAN_CHUNK; i += 256) {
    const int idx = base + i;
    sum += (idx < n) ? deg[idx] : 0;
  }
  s[threadIdx.x] = sum;
  for (int ofs = 128; ofs > 0; ofs >>= 1) {
    __syncthreads();
    if (threadIdx.x < ofs) s[threadIdx.x] += s[threadIdx.x + ofs];
  }
  __syncthreads();
  if (threadIdx.x == 0) bsum[blockIdx.x] = s[0];
}

// exclusive scan of bsum (g <= 64) in place; writes offsets[n] = total.
__global__ void scan_bsum(int* __restrict__ bsum, int g,
                          int* __restrict__ offsets, int n) {
  if (threadIdx.x == 0 && blockIdx.x == 0) {
    int run = 0;
    for (int i = 0; i < g; ++i) { const int t = bsum[i]; bsum[i] = run; run += t; }
    offsets[n] = run;
  }
}

// reads deg (may alias offsets), writes offsets[0..n) and cursor[0..n)
__global__ __launch_bounds__(256) void scan_final(
    const int* __restrict__ deg, const int* __restrict__ bsum,
    int* __restrict__ offsets, int* __restrict__ cursor, int n) {
  __shared__ int s[256];
  const int base = blockIdx.x * SCAN_CHUNK + threadIdx.x * 8;
  int v[8];
  int sum = 0;
#pragma unroll
  for (int k = 0; k < 8; ++k) {
    v[k] = (base + k < n) ? deg[base + k] : 0;
    sum += v[k];
  }
  s[threadIdx.x] = sum;
  __syncthreads();
  // Hillis-Steele inclusive scan over 256 thread sums
  for (int ofs = 1; ofs < 256; ofs <<= 1) {
    const int prev = (threadIdx.x >= ofs) ? s[threadIdx.x - ofs] : 0;
    __syncthreads();
    s[threadIdx.x] += prev;
    __syncthreads();
  }
  int run = bsum[blockIdx.x] + s[threadIdx.x] - sum;  // exclusive of this thread
#pragma unroll
  for (int k = 0; k < 8; ++k) {
    if (base + k < n) { offsets[base + k] = run; cursor[base + k] = run; }
    run += v[k];
  }
}

__global__ __launch_bounds__(256) void scatter_kernel(
    const int* __restrict__ src, const int* __restrict__ dst,
    int* __restrict__ cursor, int* __restrict__ csr_src, int nE) {
  const int e = blockIdx.x * 256 + threadIdx.x;
  if (e < nE) {
    const int pos = atomicAdd(&cursor[dst[e]], 1);
    csr_src[pos] = src[e];
  }
}

// ---------------- CSR aggregation: one wave per dst ----------------
template <int D>
__global__ __launch_bounds__(256) void agg_csr_kernel(
    const int* __restrict__ offsets, const int* __restrict__ csr_src,
    const float* __restrict__ pooled, float* __restrict__ agg, int n) {
  const int d = (int)((blockIdx.x * 256 + threadIdx.x) >> 6);
  const int lane = threadIdx.x & 63;
  if (d >= n) return;
  const int beg = offsets[d], end = offsets[d + 1];
  if (D == 128) {
    const int f = lane * 2;
    float ax = 0.f, ay = 0.f;
    int j = beg;
    for (; j + 3 < end; j += 4) {
      const int s0 = csr_src[j], s1 = csr_src[j + 1];
      const int s2 = csr_src[j + 2], s3 = csr_src[j + 3];
      const float2 v0 = *(const float2*)(pooled + (size_t)s0 * 128 + f);
      const float2 v1 = *(const float2*)(pooled + (size_t)s1 * 128 + f);
      const float2 v2 = *(const float2*)(pooled + (size_t)s2 * 128 + f);
      const float2 v3 = *(const float2*)(pooled + (size_t)s3 * 128 + f);
      ax = fmaxf(ax, fmaxf(fmaxf(v0.x, v1.x), fmaxf(v2.x, v3.x)));
      ay = fmaxf(ay, fmaxf(fmaxf(v0.y, v1.y), fmaxf(v2.y, v3.y)));
    }
    for (; j < end; ++j) {
      const int s0 = csr_src[j];
      const float2 v0 = *(const float2*)(pooled + (size_t)s0 * 128 + f);
      ax = fmaxf(ax, v0.x);
      ay = fmaxf(ay, v0.y);
    }
    float2 o; o.x = ax; o.y = ay;
    *(float2*)(agg + (size_t)d * 128 + f) = o;
  } else {
    float acc = 0.f;
    int j = beg;
    for (; j + 3 < end; j += 4) {
      const int s0 = csr_src[j], s1 = csr_src[j + 1];
      const int s2 = csr_src[j + 2], s3 = csr_src[j + 3];
      const float v0 = pooled[(size_t)s0 * 64 + lane];
      const float v1 = pooled[(size_t)s1 * 64 + lane];
      const float v2 = pooled[(size_t)s2 * 64 + lane];
      const float v3 = pooled[(size_t)s3 * 64 + lane];
      acc = fmaxf(acc, fmaxf(fmaxf(v0, v1), fmaxf(v2, v3)));
    }
    for (; j < end; ++j) {
      acc = fmaxf(acc, pooled[(size_t)csr_src[j] * 64 + lane]);
    }
    agg[(size_t)d * 64 + lane] = acc;
  }
}

// ---------------- h = relu?(A @ Wa [+ G @ Wg] + bias), DOUT=64 ----------------
template <int DIN, bool DUAL, bool RELU>
__global__ __launch_bounds__(256) void gemm_h(
    const float* __restrict__ A, const float* __restrict__ Wa,
    const float* __restrict__ G, const float* __restrict__ Wg,
    const float* __restrict__ bias, float* __restrict__ out, int n) {
  __shared__ float S[DIN][68];
  const int t = threadIdx.x;
  const int row0 = blockIdx.x * 64;
  const int tr = t & 63;
  const int tk = t >> 6;
  const int cg = t & 15, rg = t >> 4;
  const int c0 = cg * 4;
  float acc[4][4] = {};
  int gr = row0 + tr; if (gr >= n) gr = n - 1;
  const int NPASS = DUAL ? 2 : 1;
  for (int pass = 0; pass < NPASS; ++pass) {
    const float* __restrict__ P = pass ? G : A;
    const float* __restrict__ W = pass ? Wg : Wa;
    constexpr int PER_T = DIN / 16;
#pragma unroll
    for (int i = 0; i < PER_T; ++i) {
      const int k4 = (tk * PER_T + i) * 4;
      const float4 v = *(const float4*)(P + (size_t)gr * DIN + k4);
      S[k4 + 0][tr] = v.x; S[k4 + 1][tr] = v.y;
      S[k4 + 2][tr] = v.z; S[k4 + 3][tr] = v.w;
    }
    __syncthreads();
#pragma unroll 4
    for (int k = 0; k < DIN; ++k) {
      const float4 w = *(const float4*)(W + k * 64 + c0);
      const float4 a = *(const float4*)(&S[k][rg * 4]);
      acc[0][0] = fmaf(a.x, w.x, acc[0][0]);
      acc[0][1] = fmaf(a.x, w.y, acc[0][1]);
      acc[0][2] = fmaf(a.x, w.z, acc[0][2]);
      acc[0][3] = fmaf(a.x, w.w, acc[0][3]);
      acc[1][0] = fmaf(a.y, w.x, acc[1][0]);
      acc[1][1] = fmaf(a.y, w.y, acc[1][1]);
      acc[1][2] = fmaf(a.y, w.z, acc[1][2]);
      acc[1][3] = fmaf(a.y, w.w, acc[1][3]);
      acc[2][0] = fmaf(a.z, w.x, acc[2][0]);
      acc[2][1] = fmaf(a.z, w.y, acc[2][1]);
      acc[2][2] = fmaf(a.z, w.z, acc[2][2]);
      acc[2][3] = fmaf(a.z, w.w, acc[2][3]);
      acc[3][0] = fmaf(a.w, w.x, acc[3][0]);
      acc[3][1] = fmaf(a.w, w.y, acc[3][1]);
      acc[3][2] = fmaf(a.w, w.z, acc[3][2]);
      acc[3][3] = fmaf(a.w, w.w, acc[3][3]);
    }
    if (pass + 1 < NPASS) __syncthreads();
  }
  const float4 bb = *(const float4*)(bias + c0);
#pragma unroll
  for (int r = 0; r < 4; ++r) {
    const int orow = row0 + rg * 4 + r;
    if (orow < n) {
      float4 o;
      o.x = acc[r][0] + bb.x;
      o.y = acc[r][1] + bb.y;
      o.z = acc[r][2] + bb.z;
      o.w = acc[r][3] + bb.w;
      if (RELU) {
        o.x = fmaxf(o.x, 0.f); o.y = fmaxf(o.y, 0.f);
        o.z = fmaxf(o.z, 0.f); o.w = fmaxf(o.w, 0.f);
      }
      *(float4*)(out + (size_t)orow * 64 + c0) = o;
    }
  }
}

// ---------------- out[N x 2] = h2 @ W_out + b_out ----------------
__global__ __launch_bounds__(256) void out_linear(
    const float* __restrict__ h, const float* __restrict__ W,
    const float* __restrict__ b, float* __restrict__ out, int n) {
  const int node = blockIdx.x * 256 + threadIdx.x;
  if (node >= n) return;
  float a0 = b[0], a1 = b[1];
#pragma unroll
  for (int k = 0; k < 64; k += 4) {
    const float4 hv = *(const float4*)(h + (size_t)node * 64 + k);
    a0 = fmaf(hv.x, W[(k + 0) * 2 + 0], a0);
    a1 = fmaf(hv.x, W[(k + 0) * 2 + 1], a1);
    a0 = fmaf(hv.y, W[(k + 1) * 2 + 0], a0);
    a1 = fmaf(hv.y, W[(k + 1) * 2 + 1], a1);
    a0 = fmaf(hv.z, W[(k + 2) * 2 + 0], a0);
    a1 = fmaf(hv.z, W[(k + 2) * 2 + 1], a1);
    a0 = fmaf(hv.w, W[(k + 3) * 2 + 0], a0);
    a1 = fmaf(hv.w, W[(k + 3) * 2 + 1], a1);
  }
  float2 o; o.x = a0; o.y = a1;
  *(float2*)(out + (size_t)node * 2) = o;
}

extern "C" void kernel_launch(void* const* d_in, const int* in_sizes, int n_in,
                              void* d_out, int out_size, void* d_ws, size_t ws_size,
                              hipStream_t stream) {
  const float* x       = (const float*)d_in[0];
  const int*   src     = (const int*)d_in[1];
  const int*   dst     = (const int*)d_in[2];
  const float* W_pool1 = (const float*)d_in[3];
  const float* b_pool1 = (const float*)d_in[4];
  const float* W_self1 = (const float*)d_in[5];
  const float* W_neigh1= (const float*)d_in[6];
  const float* b1      = (const float*)d_in[7];
  const float* W_pool2 = (const float*)d_in[8];
  const float* b_pool2 = (const float*)d_in[9];
  const float* W_self2 = (const float*)d_in[10];
  const float* W_neigh2= (const float*)d_in[11];
  const float* b2      = (const float*)d_in[12];
  const float* W_out   = (const float*)d_in[13];
  const float* b_out   = (const float*)d_in[14];

  const int n  = in_sizes[0] / 128;
  const int nE = in_sizes[1];

  // workspace layout (floats unless noted):
  float* A   = (float*)d_ws;              // n*128: pooled1; later pooled2|agg2
  float* B   = A + (size_t)n * 128;       // n*128: agg1; later h2 (first n*64)
  float* h1  = B + (size_t)n * 128;       // n*64
  int* csr_src = (int*)(h1 + (size_t)n * 64);  // E
  int* offsets = csr_src + nE;            // n+1 (doubles as deg)
  int* cursor  = offsets + n + 1;         // n
  int* bsum    = cursor + n;              // 64
  float* outp  = (float*)d_out;

  const int G1 = (n + SCAN_CHUNK - 1) / SCAN_CHUNK;

  // ---- CSR build (deg aliases offsets[0..n)) ----
  hipMemsetAsync(offsets, 0, (size_t)n * sizeof(int), stream);
  hist_kernel<<<(nE + 255) / 256, 256, 0, stream>>>(dst, offsets, nE);
  scan_partial<<<G1, 256, 0, stream>>>(offsets, bsum, n);
  scan_bsum<<<1, 64, 0, stream>>>(bsum, G1, offsets, n);
  scan_final<<<G1, 256, 0, stream>>>(offsets, bsum, offsets, cursor, n);
  scatter_kernel<<<(nE + 255) / 256, 256, 0, stream>>>(src, dst, cursor, csr_src, nE);

  // ---- layer 1 ----
  gemm_pool1<<<(n + 31) / 32, 256, 0, stream>>>(x, W_pool1, b_pool1, A, n);
  agg_csr_kernel<128><<<(n + 3) / 4, 256, 0, stream>>>(offsets, csr_src, A, B, n);
  gemm_h<128, true, true><<<(n + 63) / 64, 256, 0, stream>>>(
      x, W_self1, B, W_neigh1, b1, h1, n);

  // ---- layer 2 ----
  float* pooled2 = A;
  float* agg2    = A + (size_t)n * 64;
  gemm_h<64, false, true><<<(n + 63) / 64, 256, 0, stream>>>(
      h1, W_pool2, nullptr, nullptr, b_pool2, pooled2, n);
  agg_csr_kernel<64><<<(n + 3) / 4, 256, 0, stream>>>(offsets, csr_src, pooled2, agg2, n);
  float* h2 = B;
  gemm_h<64, true, true><<<(n + 63) / 64, 256, 0, stream>>>(
      h1, W_self2, agg2, W_neigh2, b2, h2, n);

  // ---- head ----
  out_linear<<<(n + 255) / 256, 256, 0, stream>>>(h2, W_out, b_out, outp, n);
}